// Round 3
// baseline (1746.572 us; speedup 1.0000x reference)
//
#include <hip/hip_runtime.h>
#include <stdint.h>

// ContraNorm = 1.1*x - 0.1 * softmax(xn @ xn^T) @ x   (xn = row-L2-normalized x)
// Swapped-operand flash attention, 32x32x16 bf16 MFMA, fixed softmax shift m=1
// (cosine sim <= 1 -> exp(s-1) in (0,1], exact by shift-invariance).
// N=16384, D=256.

typedef __bf16 bf16x8 __attribute__((ext_vector_type(8)));
typedef float f32x16 __attribute__((ext_vector_type(16)));
typedef unsigned short u16;
typedef unsigned int u32;

#define GLBP __attribute__((address_space(1)))
#define LDSP __attribute__((address_space(3)))

#define NROW 16384
#define DIMD 256

__device__ __forceinline__ void g2l16(const void* g, void* l) {
  __builtin_amdgcn_global_load_lds((const GLBP u32*)g, (LDSP u32*)l, 16, 0, 0);
}

__device__ __forceinline__ u32 cvt_pk(float lo, float hi) {
  u32 r;
  asm("v_cvt_pk_bf16_f32 %0, %1, %2" : "=v"(r) : "v"(lo), "v"(hi));
  return r;
}

__device__ __forceinline__ u16 f2b(float f) {
  union { __bf16 h; u16 u; } cv; cv.h = (__bf16)f; return cv.u;
}

// ---------------------------------------------------------------------------
// Prep 1: row L2-normalize x -> xn (bf16), PRE-PACKED in MFMA fragment order:
// 32-row block rb, frag f (d-chunk of 16), lane lf: 16B granule at
//   rb*16384 + f*1024 + lf*16, elem j: row = rb*32+(lf&31), d = f*16+(lf>>5)*8+j.
__global__ void cn_norm(const float* __restrict__ x, unsigned char* __restrict__ xn) {
  const int w = threadIdx.x >> 6, l = threadIdx.x & 63;
  const int row = blockIdx.x * 4 + w;
  const float4 v = *(const float4*)(x + row * DIMD + l * 4);
  float s = v.x * v.x + v.y * v.y + v.z * v.z + v.w * v.w;
#pragma unroll
  for (int m = 1; m < 64; m <<= 1) s += __shfl_xor(s, m, 64);
  const float inv = 1.0f / fmaxf(sqrtf(s), 1e-12f);
  ushort4 o;
  o.x = f2b(v.x * inv); o.y = f2b(v.y * inv);
  o.z = f2b(v.z * inv); o.w = f2b(v.w * inv);
  const int lf = (((l >> 1) & 1) << 5) + (row & 31);
  *(ushort4*)(xn + (row >> 5) * 16384 + (l >> 2) * 1024 + lf * 16 + ((l & 1) << 3)) = o;
}

// ---------------------------------------------------------------------------
// Prep 2: V^T pre-packed A-frags: per 32-k block kb, frag fr = c*2+kh, lane ln:
// granule at kb*16384 + fr*1024 + ln*16,
// elem j: V[kb*32 + (fr&1)*16 + (ln>>5)*8 + j][(fr>>1)*32 + (ln&31)]
__global__ void cn_vtpack(const float* __restrict__ x, unsigned char* __restrict__ vt) {
  __shared__ u16 Lx[32][264];
  const int t = threadIdx.x, kb = blockIdx.x;
  {
    const int row = t >> 3, d0 = (t & 7) * 32;
    const float* src = x + (size_t)(kb * 32 + row) * DIMD + d0;
#pragma unroll
    for (int i = 0; i < 8; ++i) {
      const float4 v = *(const float4*)(src + i * 4);
      Lx[row][d0 + i * 4 + 0] = f2b(v.x);
      Lx[row][d0 + i * 4 + 1] = f2b(v.y);
      Lx[row][d0 + i * 4 + 2] = f2b(v.z);
      Lx[row][d0 + i * 4 + 3] = f2b(v.w);
    }
  }
  __syncthreads();
#pragma unroll
  for (int gi = 0; gi < 4; ++gi) {
    const int G = gi * 256 + t;
    const int fr = G >> 6, ln = G & 63;
    const int d = (fr >> 1) * 32 + (ln & 31);
    const int k0 = (fr & 1) * 16 + (ln >> 5) * 8;
    u16 pk[8];
#pragma unroll
    for (int j = 0; j < 8; ++j) pk[j] = Lx[k0 + j][d];
    *(uint4*)(vt + kb * 16384 + fr * 1024 + ln * 16) = *(const uint4*)pk;
  }
}

// ---------------------------------------------------------------------------
// Flash kernel. Block = NWQ waves x 32 q each. Grid = (N/(32*NWQ)) * NS,
// split = bid & (NS-1): with NS=8 each XCD serves exactly one 4MB k-stream
// (L2-resident). BK=32, dbuf K+V, linear global_load_lds(16B) staging,
// all ds_read_b128 linear (0 bank conflicts).
// St[k][q] = K.Q^T (A=K frag, B=Q regs); O^T[d][q] += V^T.P^T.
// C-layout (m101): col = l&31 (=q), row = (r&3)+8*(r>>2)+4*(l>>5).
template <int NS, int NWQ, bool DIRECT>
__global__ __launch_bounds__(64 * NWQ, 4) void cn_flash(
    const unsigned char* __restrict__ xn,
    const unsigned char* __restrict__ vt,
    unsigned char* __restrict__ Po,   // bf16 [NS][256][16384]
    float* __restrict__ Ls,           // f32 [NS][2][16384]
    const float* __restrict__ x,      // DIRECT only
    float* __restrict__ out) {        // DIRECT only
  constexpr int SH = (NS == 8) ? 3 : (NS == 4) ? 2 : (NS == 2) ? 1 : 0;
  constexpr int KT = NROW / (32 * NS);
  constexpr int TPB = 64 * NWQ;
  constexpr int RS = 16384 / (TPB * 16);  // staging rounds per buffer
  __shared__ __align__(16) unsigned char sK[2][16384];
  __shared__ __align__(16) unsigned char sV[2][16384];
  const int tid = threadIdx.x;
  const int w = tid >> 6, l = tid & 63;
  const int bid = blockIdx.x;
  const int split = bid & (NS - 1), qblk = bid >> SH;
  const int q0 = qblk * (32 * NWQ) + w * 32;
  const int lq = l & 31, hi = l >> 5;

  const size_t gbase = (size_t)split * KT * 16384;
  // prologue: stage tile 0
#pragma unroll
  for (int r = 0; r < RS; ++r) {
    const int off = (r * TPB + tid) * 16;
    g2l16(xn + gbase + off, &sK[0][off]);
    g2l16(vt + gbase + off, &sV[0][off]);
  }
  // Q fragments (B-operand, n = q = l&31, k-chunk = (l>>5)*8+j)
  bf16x8 Qf[16];
  {
    const unsigned char* qb = xn + (size_t)(q0 >> 5) * 16384;
#pragma unroll
    for (int f = 0; f < 16; ++f) Qf[f] = *(const bf16x8*)(qb + f * 1024 + l * 16);
  }

  f32x16 O[8];
#pragma unroll
  for (int c = 0; c < 8; ++c)
#pragma unroll
    for (int r = 0; r < 16; ++r) O[c][r] = 0.f;
  float lsum = 0.f;

  __syncthreads();

  for (int t = 0; t < KT; ++t) {
    const int cur = t & 1;
    if (t + 1 < KT) {  // prefetch next tile into other buffer
      const size_t gt = gbase + (size_t)(t + 1) * 16384;
      const int nb = cur ^ 1;
#pragma unroll
      for (int r = 0; r < RS; ++r) {
        const int off = (r * TPB + tid) * 16;
        g2l16(xn + gt + off, &sK[nb][off]);
        g2l16(vt + gt + off, &sV[nb][off]);
      }
    }
    const unsigned char* Kb = &sK[cur][0];
    const unsigned char* Vb = &sV[cur][0];

    // ---- St[32k][32q] = K . Q^T over d=256 (16 frags)
    f32x16 St;
#pragma unroll
    for (int r = 0; r < 16; ++r) St[r] = 0.f;
    __builtin_amdgcn_s_setprio(1);
#pragma unroll
    for (int f = 0; f < 16; ++f) {
      const bf16x8 ka = *(const bf16x8*)(Kb + f * 1024 + l * 16);
      St = __builtin_amdgcn_mfma_f32_32x32x16_bf16(ka, Qf[f], St, 0, 0, 0);
    }
    __builtin_amdgcn_s_setprio(0);

    // ---- p = exp(s - 1) (fixed shift; exact), lane-local rowsum
    float p[16];
#pragma unroll
    for (int r = 0; r < 16; ++r) {
      p[r] = __expf(St[r] - 1.0f);
      lsum += p[r];
    }
    // ---- pack P^T B-frags: cvt_pk + permlane32_swap (no LDS)
    u32 a0 = cvt_pk(p[0], p[1]), a1 = cvt_pk(p[2], p[3]);
    u32 b0 = cvt_pk(p[4], p[5]), b1 = cvt_pk(p[6], p[7]);
    asm("v_permlane32_swap_b32 %0, %1" : "+v"(a0), "+v"(b0));
    asm("v_permlane32_swap_b32 %0, %1" : "+v"(a1), "+v"(b1));
    u32 c0 = cvt_pk(p[8], p[9]), c1 = cvt_pk(p[10], p[11]);
    u32 d0 = cvt_pk(p[12], p[13]), d1 = cvt_pk(p[14], p[15]);
    asm("v_permlane32_swap_b32 %0, %1" : "+v"(c0), "+v"(d0));
    asm("v_permlane32_swap_b32 %0, %1" : "+v"(c1), "+v"(d1));
    union PW { u32 w[4]; bf16x8 v; } pf0, pf1;
    pf0.w[0] = a0; pf0.w[1] = a1; pf0.w[2] = b0; pf0.w[3] = b1;
    pf1.w[0] = c0; pf1.w[1] = c1; pf1.w[2] = d0; pf1.w[3] = d1;

    // ---- O^T[d][q] += V^T . P^T  (8 d-chunks x 2 k-halves)
    __builtin_amdgcn_s_setprio(1);
#pragma unroll
    for (int c = 0; c < 8; ++c) {
      const bf16x8 va0 = *(const bf16x8*)(Vb + (c * 2 + 0) * 1024 + l * 16);
      O[c] = __builtin_amdgcn_mfma_f32_32x32x16_bf16(va0, pf0.v, O[c], 0, 0, 0);
      const bf16x8 va1 = *(const bf16x8*)(Vb + (c * 2 + 1) * 1024 + l * 16);
      O[c] = __builtin_amdgcn_mfma_f32_32x32x16_bf16(va1, pf1.v, O[c], 0, 0, 0);
    }
    __builtin_amdgcn_s_setprio(0);
    __syncthreads();
  }

  // ---- epilogue
  const int qc = q0 + lq;
  if (DIRECT) {
    const float Lt = lsum + __shfl_xor(lsum, 32, 64);
    const float sc = 0.1f / Lt;
#pragma unroll
    for (int c = 0; c < 8; ++c)
#pragma unroll
      for (int r = 0; r < 16; ++r) {
        const int d = c * 32 + (r & 3) + 8 * (r >> 2) + 4 * hi;
        out[(size_t)qc * DIMD + d] =
            1.1f * x[(size_t)qc * DIMD + d] - sc * O[c][r];
      }
  } else {
#pragma unroll
    for (int c = 0; c < 8; ++c)
#pragma unroll
      for (int r = 0; r < 16; ++r) {
        const int d = c * 32 + (r & 3) + 8 * (r >> 2) + 4 * hi;
        *(u16*)(Po + ((size_t)split * DIMD + d) * 32768 + (size_t)qc * 2) = f2b(O[c][r]);
      }
    Ls[(size_t)(split * 2 + hi) * NROW + qc] = lsum;
  }
}

// ---------------------------------------------------------------------------
// Merge: out[q][d] = 1.1 x - 0.1 * (sum_s Po[s][d][q]) / (sum_s,h Ls[s][h][q])
template <int NS>
__global__ void cn_merge(const float* __restrict__ x,
                         const unsigned char* __restrict__ Po,
                         const float* __restrict__ Ls,
                         float* __restrict__ out) {
  __shared__ float acc[256][65];
  __shared__ float Lq[64];
  const int t = threadIdx.x;
  const int q0 = blockIdx.x * 64;
  const int dloc = t >> 3, ch = t & 7;
#pragma unroll
  for (int pass = 0; pass < 8; ++pass) {
    const int d = pass * 32 + dloc;
    float a[8] = {0.f, 0.f, 0.f, 0.f, 0.f, 0.f, 0.f, 0.f};
#pragma unroll
    for (int s = 0; s < NS; ++s) {
      const uint4 v = *(const uint4*)(Po + ((size_t)(s * 256 + d)) * 32768 +
                                      (size_t)q0 * 2 + ch * 16);
      const u32 wv[4] = {v.x, v.y, v.z, v.w};
#pragma unroll
      for (int k = 0; k < 4; ++k) {
        a[2 * k + 0] += __uint_as_float(wv[k] << 16);
        a[2 * k + 1] += __uint_as_float(wv[k] & 0xffff0000u);
      }
    }
#pragma unroll
    for (int j = 0; j < 8; ++j) acc[d][ch * 8 + j] = a[j];
  }
  if (t < 64) {
    const int q = q0 + t;
    float L = 0.f;
#pragma unroll
    for (int s = 0; s < NS; ++s)
      L += Ls[(size_t)(s * 2 + 0) * NROW + q] + Ls[(size_t)(s * 2 + 1) * NROW + q];
    Lq[t] = 1.0f / L;
  }
  __syncthreads();
  const int ql = t >> 2, dd0 = (t & 3) * 64;
  const float inv = Lq[ql];
  const int q = q0 + ql;
#pragma unroll
  for (int i = 0; i < 64; i += 4) {
    const float4 xv = *(const float4*)(x + (size_t)q * DIMD + dd0 + i);
    float4 ov;
    ov.x = 1.1f * xv.x - 0.1f * acc[dd0 + i + 0][ql] * inv;
    ov.y = 1.1f * xv.y - 0.1f * acc[dd0 + i + 1][ql] * inv;
    ov.z = 1.1f * xv.z - 0.1f * acc[dd0 + i + 2][ql] * inv;
    ov.w = 1.1f * xv.w - 0.1f * acc[dd0 + i + 3][ql] * inv;
    *(float4*)(out + (size_t)q * DIMD + dd0 + i) = ov;
  }
}

// ---------------------------------------------------------------------------
extern "C" void kernel_launch(void* const* d_in, const int* in_sizes, int n_in,
                              void* d_out, int out_size, void* d_ws, size_t ws_size,
                              hipStream_t stream) {
  const float* x = (const float*)d_in[0];
  float* out = (float*)d_out;
  unsigned char* xn = (unsigned char*)d_ws;                      // 8 MB packed bf16 x_norm
  unsigned char* vt = xn + (size_t)8 * 1024 * 1024;              // 8 MB packed bf16 V^T
  unsigned char* Po = vt + (size_t)8 * 1024 * 1024;              // NS * 8 MB bf16 partials

  cn_norm<<<4096, 256, 0, stream>>>(x, xn);
  cn_vtpack<<<512, 256, 0, stream>>>(x, vt);

  const size_t need8 = (size_t)(16 + 64) * 1024 * 1024 + 1024 * 1024;
  const size_t need4 = (size_t)(16 + 32) * 1024 * 1024 + 512 * 1024;
  const size_t need2 = (size_t)(16 + 16) * 1024 * 1024 + 256 * 1024;
  if (ws_size >= need8) {
    // 512 blocks x 8 waves: 2 blocks/CU, 16 waves/CU; XCD i <-> split i (L2-resident)
    float* Ls = (float*)(Po + (size_t)8 * 8 * 1024 * 1024);
    cn_flash<8, 8, false><<<512, 512, 0, stream>>>(xn, vt, Po, Ls, x, out);
    cn_merge<8><<<256, 256, 0, stream>>>(x, Po, Ls, out);
  } else if (ws_size >= need4) {
    float* Ls = (float*)(Po + (size_t)4 * 8 * 1024 * 1024);
    cn_flash<4, 4, false><<<512, 256, 0, stream>>>(xn, vt, Po, Ls, x, out);
    cn_merge<4><<<256, 256, 0, stream>>>(x, Po, Ls, out);
  } else if (ws_size >= need2) {
    float* Ls = (float*)(Po + (size_t)2 * 8 * 1024 * 1024);
    cn_flash<2, 4, false><<<256, 256, 0, stream>>>(xn, vt, Po, Ls, x, out);
    cn_merge<2><<<256, 256, 0, stream>>>(x, Po, Ls, out);
  } else {
    cn_flash<1, 4, true><<<128, 256, 0, stream>>>(xn, vt, nullptr, nullptr, x, out);
  }
}

// Round 4
// 478.555 us; speedup vs baseline: 3.6497x; 3.6497x over previous
//
#include <hip/hip_runtime.h>
#include <stdint.h>

// ContraNorm = 1.1*x - 0.1 * softmax(xn @ xn^T) @ x   (xn = row-L2-normalized x)
// Swapped-operand flash attention, 32x32x16 bf16 MFMA, fixed softmax shift m=1
// (cosine sim <= 1 -> exp(s-1) in (0,1], exact by shift-invariance).
// Round 4: K via LDS (dbuf BK=64), V mostly DIRECT from global (L2-resident,
// 14/16 frags) to split traffic across LDS + L2 pipes. launch_bounds(256,2)
// ONLY (round-3 lesson: min-waves>2 halves reg budget -> catastrophic spill).
// N=16384, D=256.

typedef __bf16 bf16x8 __attribute__((ext_vector_type(8)));
typedef float f32x16 __attribute__((ext_vector_type(16)));
typedef unsigned short u16;
typedef unsigned int u32;

#define GLBP __attribute__((address_space(1)))
#define LDSP __attribute__((address_space(3)))

#define NROW 16384
#define DIMD 256

__device__ __forceinline__ void g2l16(const void* g, void* l) {
  __builtin_amdgcn_global_load_lds((const GLBP u32*)g, (LDSP u32*)l, 16, 0, 0);
}

__device__ __forceinline__ u32 cvt_pk(float lo, float hi) {
  u32 r;
  asm("v_cvt_pk_bf16_f32 %0, %1, %2" : "=v"(r) : "v"(lo), "v"(hi));
  return r;
}

__device__ __forceinline__ u16 f2b(float f) {
  union { __bf16 h; u16 u; } cv; cv.h = (__bf16)f; return cv.u;
}

// ---------------------------------------------------------------------------
// Prep 1: row L2-normalize x -> xn (bf16), PRE-PACKED in MFMA fragment order:
// 32-row block rb, frag f (d-chunk of 16), lane lf: 16B granule at
//   rb*16384 + f*1024 + lf*16, elem j: row = rb*32+(lf&31), d = f*16+(lf>>5)*8+j.
__global__ void cn_norm(const float* __restrict__ x, unsigned char* __restrict__ xn) {
  const int w = threadIdx.x >> 6, l = threadIdx.x & 63;
  const int row = blockIdx.x * 4 + w;
  const float4 v = *(const float4*)(x + row * DIMD + l * 4);
  float s = v.x * v.x + v.y * v.y + v.z * v.z + v.w * v.w;
#pragma unroll
  for (int m = 1; m < 64; m <<= 1) s += __shfl_xor(s, m, 64);
  const float inv = 1.0f / fmaxf(sqrtf(s), 1e-12f);
  ushort4 o;
  o.x = f2b(v.x * inv); o.y = f2b(v.y * inv);
  o.z = f2b(v.z * inv); o.w = f2b(v.w * inv);
  const int lf = (((l >> 1) & 1) << 5) + (row & 31);
  *(ushort4*)(xn + (row >> 5) * 16384 + (l >> 2) * 1024 + lf * 16 + ((l & 1) << 3)) = o;
}

// ---------------------------------------------------------------------------
// Prep 2: V^T pre-packed A-frags: per 32-k block kb, frag fr = c*2+kh, lane ln:
// granule at kb*16384 + fr*1024 + ln*16,
// elem j: V[kb*32 + (fr&1)*16 + (ln>>5)*8 + j][(fr>>1)*32 + (ln&31)]
__global__ void cn_vtpack(const float* __restrict__ x, unsigned char* __restrict__ vt) {
  __shared__ u16 Lx[32][264];
  const int t = threadIdx.x, kb = blockIdx.x;
  {
    const int row = t >> 3, d0 = (t & 7) * 32;
    const float* src = x + (size_t)(kb * 32 + row) * DIMD + d0;
#pragma unroll
    for (int i = 0; i < 8; ++i) {
      const float4 v = *(const float4*)(src + i * 4);
      Lx[row][d0 + i * 4 + 0] = f2b(v.x);
      Lx[row][d0 + i * 4 + 1] = f2b(v.y);
      Lx[row][d0 + i * 4 + 2] = f2b(v.z);
      Lx[row][d0 + i * 4 + 3] = f2b(v.w);
    }
  }
  __syncthreads();
#pragma unroll
  for (int gi = 0; gi < 4; ++gi) {
    const int G = gi * 256 + t;
    const int fr = G >> 6, ln = G & 63;
    const int d = (fr >> 1) * 32 + (ln & 31);
    const int k0 = (fr & 1) * 16 + (ln >> 5) * 8;
    u16 pk[8];
#pragma unroll
    for (int j = 0; j < 8; ++j) pk[j] = Lx[k0 + j][d];
    *(uint4*)(vt + kb * 16384 + fr * 1024 + ln * 16) = *(const uint4*)pk;
  }
}

// ---------------------------------------------------------------------------
// Flash kernel. Block = 4 waves x 32 q each (128 q). Grid = (N/128) * NS,
// split = bid & (NS-1): with NS=8 each XCD serves exactly one 2MB K-stream +
// 2MB V-stream (L2-resident). K: BK=64 double-buffered LDS via
// global_load_lds(16B), one barrier per 64k. V: frags 0..13 DIRECT from
// global (L2), frags 14,15 via small LDS stage (pipe balancing).
// St[k][q] = K.Q^T (A=K frag, B=Q regs); O^T[d][q] += V^T.P^T.
// C-layout (m101): col = l&31 (=q), row = (r&3)+8*(r>>2)+4*(l>>5).
template <int NS, bool DIRECT>
__global__ __launch_bounds__(256, 2) void cn_flash(
    const unsigned char* __restrict__ xn,
    const unsigned char* __restrict__ vt,
    unsigned char* __restrict__ Po,   // bf16 [NS][256][16384]
    float* __restrict__ Ls,           // f32 [NS][2][16384]
    const float* __restrict__ x,      // DIRECT only
    float* __restrict__ out) {        // DIRECT only
  constexpr int SH = (NS == 8) ? 3 : (NS == 4) ? 2 : (NS == 2) ? 1 : 0;
  constexpr int KB32 = NROW / (32 * NS);  // 32k-blocks per split
  constexpr int KT2 = KB32 / 2;           // 64k double-tiles
  __shared__ __align__(16) unsigned char sK[2][32768];
  __shared__ __align__(16) unsigned char sVq[2][4096];
  const int tid = threadIdx.x;
  const int w = tid >> 6, l = tid & 63;
  const int bid = blockIdx.x;
  const int split = bid & (NS - 1), qblk = bid >> SH;
  const int q0 = qblk * 128 + w * 32;
  const int lq = l & 31, hi = l >> 5;

  const size_t gbase = (size_t)split * KB32 * 16384;
  const int vchunk = tid >> 7, voffb = (tid & 127) * 16;
  // prologue: stage double-tile 0 (K 32KB + V-tail 4KB)
#pragma unroll
  for (int r = 0; r < 8; ++r) {
    const int off = r * 4096 + tid * 16;
    g2l16(xn + gbase + off, &sK[0][off]);
  }
  g2l16(vt + gbase + (size_t)vchunk * 16384 + 14336 + voffb, &sVq[0][vchunk * 2048 + voffb]);

  // Q fragments (B-operand, n = q = l&31, k-chunk = (l>>5)*8+j)
  bf16x8 Qf[16];
  {
    const unsigned char* qb = xn + (size_t)(q0 >> 5) * 16384;
#pragma unroll
    for (int f = 0; f < 16; ++f) Qf[f] = *(const bf16x8*)(qb + f * 1024 + l * 16);
  }

  f32x16 O[8];
#pragma unroll
  for (int c = 0; c < 8; ++c)
#pragma unroll
    for (int r = 0; r < 16; ++r) O[c][r] = 0.f;
  float lsum = 0.f;
  const float L2E = 1.442695041f;

  __syncthreads();

  for (int T = 0; T < KT2; ++T) {
    const int cur = T & 1;
    if (T + 1 < KT2) {  // prefetch next double-tile into other buffer
      const size_t gt = gbase + (size_t)(T + 1) * 32768;
      const int nb = cur ^ 1;
#pragma unroll
      for (int r = 0; r < 8; ++r) {
        const int off = r * 4096 + tid * 16;
        g2l16(xn + gt + off, &sK[nb][off]);
      }
      g2l16(vt + gt + (size_t)vchunk * 16384 + 14336 + voffb,
            &sVq[nb][vchunk * 2048 + voffb]);
    }
#pragma unroll
    for (int ss = 0; ss < 2; ++ss) {
      const unsigned char* Kb = &sK[cur][ss * 16384];
      const bf16x8* Vg = (const bf16x8*)(vt + gbase + ((size_t)(2 * T + ss)) * 16384);
      const unsigned char* Vq = &sVq[cur][ss * 2048];

      // ---- St[32k][32q] = K . Q^T over d=256 (16 frags)
      f32x16 St;
#pragma unroll
      for (int r = 0; r < 16; ++r) St[r] = 0.f;
      __builtin_amdgcn_s_setprio(1);
#pragma unroll
      for (int f = 0; f < 16; ++f) {
        const bf16x8 ka = *(const bf16x8*)(Kb + f * 1024 + l * 16);
        St = __builtin_amdgcn_mfma_f32_32x32x16_bf16(ka, Qf[f], St, 0, 0, 0);
      }
      __builtin_amdgcn_s_setprio(0);

      // ---- p = exp(s - 1) = exp2(s*log2e - log2e) (fixed shift; exact)
      float p[16];
#pragma unroll
      for (int r = 0; r < 16; ++r) {
        p[r] = exp2f(fmaf(St[r], L2E, -L2E));
        lsum += p[r];
      }
      // ---- pack P^T B-frags: cvt_pk + permlane32_swap (no LDS)
      u32 a0 = cvt_pk(p[0], p[1]), a1 = cvt_pk(p[2], p[3]);
      u32 b0 = cvt_pk(p[4], p[5]), b1 = cvt_pk(p[6], p[7]);
      asm("v_permlane32_swap_b32 %0, %1" : "+v"(a0), "+v"(b0));
      asm("v_permlane32_swap_b32 %0, %1" : "+v"(a1), "+v"(b1));
      u32 c0 = cvt_pk(p[8], p[9]), c1 = cvt_pk(p[10], p[11]);
      u32 d0 = cvt_pk(p[12], p[13]), d1 = cvt_pk(p[14], p[15]);
      asm("v_permlane32_swap_b32 %0, %1" : "+v"(c0), "+v"(d0));
      asm("v_permlane32_swap_b32 %0, %1" : "+v"(c1), "+v"(d1));
      union PW { u32 w[4]; bf16x8 v; } pf0, pf1;
      pf0.w[0] = a0; pf0.w[1] = a1; pf0.w[2] = b0; pf0.w[3] = b1;
      pf1.w[0] = c0; pf1.w[1] = c1; pf1.w[2] = d0; pf1.w[3] = d1;

      // ---- O^T[d][q] += V^T . P^T  (c=0..6 direct from L2; c=7 via LDS)
      __builtin_amdgcn_s_setprio(1);
#pragma unroll
      for (int c = 0; c < 7; ++c) {
        const bf16x8 va0 = Vg[(c * 2 + 0) * 64 + l];
        O[c] = __builtin_amdgcn_mfma_f32_32x32x16_bf16(va0, pf0.v, O[c], 0, 0, 0);
        const bf16x8 va1 = Vg[(c * 2 + 1) * 64 + l];
        O[c] = __builtin_amdgcn_mfma_f32_32x32x16_bf16(va1, pf1.v, O[c], 0, 0, 0);
      }
      {
        const bf16x8 va0 = *(const bf16x8*)(Vq + l * 16);
        O[7] = __builtin_amdgcn_mfma_f32_32x32x16_bf16(va0, pf0.v, O[7], 0, 0, 0);
        const bf16x8 va1 = *(const bf16x8*)(Vq + 1024 + l * 16);
        O[7] = __builtin_amdgcn_mfma_f32_32x32x16_bf16(va1, pf1.v, O[7], 0, 0, 0);
      }
      __builtin_amdgcn_s_setprio(0);
    }
    __syncthreads();
  }

  // ---- epilogue
  const int qc = q0 + lq;
  if (DIRECT) {
    const float Lt = lsum + __shfl_xor(lsum, 32, 64);
    const float sc = 0.1f / Lt;
#pragma unroll
    for (int c = 0; c < 8; ++c)
#pragma unroll
      for (int r = 0; r < 16; ++r) {
        const int d = c * 32 + (r & 3) + 8 * (r >> 2) + 4 * hi;
        out[(size_t)qc * DIMD + d] =
            1.1f * x[(size_t)qc * DIMD + d] - sc * O[c][r];
      }
  } else {
#pragma unroll
    for (int c = 0; c < 8; ++c)
#pragma unroll
      for (int r = 0; r < 16; ++r) {
        const int d = c * 32 + (r & 3) + 8 * (r >> 2) + 4 * hi;
        *(u16*)(Po + ((size_t)split * DIMD + d) * 32768 + (size_t)qc * 2) = f2b(O[c][r]);
      }
    Ls[(size_t)(split * 2 + hi) * NROW + qc] = lsum;
  }
}

// ---------------------------------------------------------------------------
// Merge: out[q][d] = 1.1 x - 0.1 * (sum_s Po[s][d][q]) / (sum_s,h Ls[s][h][q])
template <int NS>
__global__ void cn_merge(const float* __restrict__ x,
                         const unsigned char* __restrict__ Po,
                         const float* __restrict__ Ls,
                         float* __restrict__ out) {
  __shared__ float acc[256][65];
  __shared__ float Lq[64];
  const int t = threadIdx.x;
  const int q0 = blockIdx.x * 64;
  const int dloc = t >> 3, ch = t & 7;
#pragma unroll
  for (int pass = 0; pass < 8; ++pass) {
    const int d = pass * 32 + dloc;
    float a[8] = {0.f, 0.f, 0.f, 0.f, 0.f, 0.f, 0.f, 0.f};
#pragma unroll
    for (int s = 0; s < NS; ++s) {
      const uint4 v = *(const uint4*)(Po + ((size_t)(s * 256 + d)) * 32768 +
                                      (size_t)q0 * 2 + ch * 16);
      const u32 wv[4] = {v.x, v.y, v.z, v.w};
#pragma unroll
      for (int k = 0; k < 4; ++k) {
        a[2 * k + 0] += __uint_as_float(wv[k] << 16);
        a[2 * k + 1] += __uint_as_float(wv[k] & 0xffff0000u);
      }
    }
#pragma unroll
    for (int j = 0; j < 8; ++j) acc[d][ch * 8 + j] = a[j];
  }
  if (t < 64) {
    const int q = q0 + t;
    float L = 0.f;
#pragma unroll
    for (int s = 0; s < NS; ++s)
      L += Ls[(size_t)(s * 2 + 0) * NROW + q] + Ls[(size_t)(s * 2 + 1) * NROW + q];
    Lq[t] = 1.0f / L;
  }
  __syncthreads();
  const int ql = t >> 2, dd0 = (t & 3) * 64;
  const float inv = Lq[ql];
  const int q = q0 + ql;
#pragma unroll
  for (int i = 0; i < 64; i += 4) {
    const float4 xv = *(const float4*)(x + (size_t)q * DIMD + dd0 + i);
    float4 ov;
    ov.x = 1.1f * xv.x - 0.1f * acc[dd0 + i + 0][ql] * inv;
    ov.y = 1.1f * xv.y - 0.1f * acc[dd0 + i + 1][ql] * inv;
    ov.z = 1.1f * xv.z - 0.1f * acc[dd0 + i + 2][ql] * inv;
    ov.w = 1.1f * xv.w - 0.1f * acc[dd0 + i + 3][ql] * inv;
    *(float4*)(out + (size_t)q * DIMD + dd0 + i) = ov;
  }
}

// ---------------------------------------------------------------------------
extern "C" void kernel_launch(void* const* d_in, const int* in_sizes, int n_in,
                              void* d_out, int out_size, void* d_ws, size_t ws_size,
                              hipStream_t stream) {
  const float* x = (const float*)d_in[0];
  float* out = (float*)d_out;
  unsigned char* xn = (unsigned char*)d_ws;                      // 8 MB packed bf16 x_norm
  unsigned char* vt = xn + (size_t)8 * 1024 * 1024;              // 8 MB packed bf16 V^T
  unsigned char* Po = vt + (size_t)8 * 1024 * 1024;              // NS * 8 MB bf16 partials

  cn_norm<<<4096, 256, 0, stream>>>(x, xn);
  cn_vtpack<<<512, 256, 0, stream>>>(x, vt);

  const size_t need8 = (size_t)(16 + 64) * 1024 * 1024 + 1024 * 1024;
  const size_t need4 = (size_t)(16 + 32) * 1024 * 1024 + 512 * 1024;
  const size_t need2 = (size_t)(16 + 16) * 1024 * 1024 + 256 * 1024;
  if (ws_size >= need8) {
    // 1024 blocks x 4 waves; XCD i <-> split i (2MB K + 2MB V L2-resident)
    float* Ls = (float*)(Po + (size_t)8 * 8 * 1024 * 1024);
    cn_flash<8, false><<<1024, 256, 0, stream>>>(xn, vt, Po, Ls, x, out);
    cn_merge<8><<<256, 256, 0, stream>>>(x, Po, Ls, out);
  } else if (ws_size >= need4) {
    float* Ls = (float*)(Po + (size_t)4 * 8 * 1024 * 1024);
    cn_flash<4, false><<<512, 256, 0, stream>>>(xn, vt, Po, Ls, x, out);
    cn_merge<4><<<256, 256, 0, stream>>>(x, Po, Ls, out);
  } else if (ws_size >= need2) {
    float* Ls = (float*)(Po + (size_t)2 * 8 * 1024 * 1024);
    cn_flash<2, false><<<256, 256, 0, stream>>>(xn, vt, Po, Ls, x, out);
    cn_merge<2><<<256, 256, 0, stream>>>(x, Po, Ls, out);
  } else {
    cn_flash<1, true><<<128, 256, 0, stream>>>(xn, vt, nullptr, nullptr, x, out);
  }
}

// Round 6
// 340.459 us; speedup vs baseline: 5.1301x; 1.4056x over previous
//
#include <hip/hip_runtime.h>
#include <stdint.h>

// ContraNorm = 1.1*x - 0.1 * softmax(xn @ xn^T) @ x   (xn = row-L2-normalized x)
// Swapped-operand flash attention, 32x32x16 bf16 MFMA, fixed softmax shift m=1
// (cosine sim <= 1 -> exp(s-1) in (0,1], exact by shift-invariance).
// Round 5 (resubmit; round-5 bench was a broker timeout) = round-2 structure
// (250us) + reg-neutral edits:
//  - V frags 0..3 (c=0,1) read DIRECT from L2 with EXPLICIT early issue
//    (issued post-QK^T, consumed in PV; ~300cy cover). LDS traffic -12.5%.
//  - PV MFMA reorder (kh0 pass then kh1 pass): no back-to-back same-acc MFMA.
//  - lsum tree reduction (breaks 16-deep serial fp add chain).
// Register budget is EXACTLY full (128 VGPR + 128 acc = 256 -> 2 waves/SIMD).
// NEVER raise launch_bounds min-waves above 2 (round-3 spill disaster).
// N=16384, D=256.

typedef __bf16 bf16x8 __attribute__((ext_vector_type(8)));
typedef float f32x16 __attribute__((ext_vector_type(16)));
typedef unsigned short u16;
typedef unsigned int u32;

#define GLBP __attribute__((address_space(1)))
#define LDSP __attribute__((address_space(3)))

#define NROW 16384
#define DIMD 256

__device__ __forceinline__ void g2l16(const void* g, void* l) {
  __builtin_amdgcn_global_load_lds((const GLBP u32*)g, (LDSP u32*)l, 16, 0, 0);
}

__device__ __forceinline__ u32 cvt_pk(float lo, float hi) {
  u32 r;
  asm("v_cvt_pk_bf16_f32 %0, %1, %2" : "=v"(r) : "v"(lo), "v"(hi));
  return r;
}

__device__ __forceinline__ u16 f2b(float f) {
  union { __bf16 h; u16 u; } cv; cv.h = (__bf16)f; return cv.u;
}

// ---------------------------------------------------------------------------
// Prep 1: row L2-normalize x -> xn (bf16), PRE-PACKED in MFMA fragment order:
// 32-row block rb, frag f (d-chunk of 16), lane lf: 16B granule at
//   rb*16384 + f*1024 + lf*16, elem j: row = rb*32+(lf&31), d = f*16+(lf>>5)*8+j.
__global__ void cn_norm(const float* __restrict__ x, unsigned char* __restrict__ xn) {
  const int w = threadIdx.x >> 6, l = threadIdx.x & 63;
  const int row = blockIdx.x * 4 + w;
  const float4 v = *(const float4*)(x + row * DIMD + l * 4);
  float s = v.x * v.x + v.y * v.y + v.z * v.z + v.w * v.w;
#pragma unroll
  for (int m = 1; m < 64; m <<= 1) s += __shfl_xor(s, m, 64);
  const float inv = 1.0f / fmaxf(sqrtf(s), 1e-12f);
  ushort4 o;
  o.x = f2b(v.x * inv); o.y = f2b(v.y * inv);
  o.z = f2b(v.z * inv); o.w = f2b(v.w * inv);
  const int lf = (((l >> 1) & 1) << 5) + (row & 31);
  *(ushort4*)(xn + (row >> 5) * 16384 + (l >> 2) * 1024 + lf * 16 + ((l & 1) << 3)) = o;
}

// ---------------------------------------------------------------------------
// Prep 2: V^T pre-packed A-frags: per 32-k block kb, frag fr = c*2+kh, lane ln:
// granule at kb*16384 + fr*1024 + ln*16,
// elem j: V[kb*32 + (fr&1)*16 + (ln>>5)*8 + j][(fr>>1)*32 + (ln&31)]
__global__ void cn_vtpack(const float* __restrict__ x, unsigned char* __restrict__ vt) {
  __shared__ u16 Lx[32][264];
  const int t = threadIdx.x, kb = blockIdx.x;
  {
    const int row = t >> 3, d0 = (t & 7) * 32;
    const float* src = x + (size_t)(kb * 32 + row) * DIMD + d0;
#pragma unroll
    for (int i = 0; i < 8; ++i) {
      const float4 v = *(const float4*)(src + i * 4);
      Lx[row][d0 + i * 4 + 0] = f2b(v.x);
      Lx[row][d0 + i * 4 + 1] = f2b(v.y);
      Lx[row][d0 + i * 4 + 2] = f2b(v.z);
      Lx[row][d0 + i * 4 + 3] = f2b(v.w);
    }
  }
  __syncthreads();
#pragma unroll
  for (int gi = 0; gi < 4; ++gi) {
    const int G = gi * 256 + t;
    const int fr = G >> 6, ln = G & 63;
    const int d = (fr >> 1) * 32 + (ln & 31);
    const int k0 = (fr & 1) * 16 + (ln >> 5) * 8;
    u16 pk[8];
#pragma unroll
    for (int j = 0; j < 8; ++j) pk[j] = Lx[k0 + j][d];
    *(uint4*)(vt + kb * 16384 + fr * 1024 + ln * 16) = *(const uint4*)pk;
  }
}

// ---------------------------------------------------------------------------
// Flash kernel. Block = 4 waves x 32 q each (128 q). Grid = (N/128) * NS,
// split = bid & (NS-1). BK=32: K (16KB) + V-frags-4..15 (12KB) double-buffered
// LDS via global_load_lds(16B); V frags 0..3 (c=0,1) DIRECT from L2, issued
// explicitly post-QK^T (latency hidden under softmax).
// St[k][q] = K.Q^T (A=K frag, B=Q regs); O^T[d][q] += V^T.P^T.
// C-layout (m101): col = l&31 (=q), row = (r&3)+8*(r>>2)+4*(l>>5).
template <int NS, bool DIRECT>
__global__ __launch_bounds__(256, 2) void cn_flash(
    const unsigned char* __restrict__ xn,
    const unsigned char* __restrict__ vt,
    unsigned char* __restrict__ Po,   // bf16 [NS][256][16384]
    float* __restrict__ Ls,           // f32 [NS][2][16384]
    const float* __restrict__ x,      // DIRECT only
    float* __restrict__ out) {        // DIRECT only
  constexpr int SH = (NS == 8) ? 3 : (NS == 4) ? 2 : (NS == 2) ? 1 : 0;
  constexpr int KT = NROW / (32 * NS);
  __shared__ __align__(16) unsigned char sK[2][16384];
  __shared__ __align__(16) unsigned char sV[2][12288];
  const int tid = threadIdx.x;
  const int w = tid >> 6, l = tid & 63;
  const int bid = blockIdx.x;
  const int split = bid & (NS - 1), qblk = bid >> SH;
  const int q0 = qblk * 128 + w * 32;
  const int lq = l & 31, hi = l >> 5;

  const size_t gbase = (size_t)split * KT * 16384;
  // prologue: stage tile 0 (K 16KB + V frags 4..15 = 12KB)
#pragma unroll
  for (int r = 0; r < 4; ++r)
    g2l16(xn + gbase + r * 4096 + tid * 16, &sK[0][r * 4096 + tid * 16]);
#pragma unroll
  for (int r = 0; r < 3; ++r)
    g2l16(vt + gbase + 4096 + r * 4096 + tid * 16, &sV[0][r * 4096 + tid * 16]);

  // Q fragments (B-operand, n = q = l&31, k-chunk = (l>>5)*8+j)
  bf16x8 Qf[16];
  {
    const unsigned char* qb = xn + (size_t)(q0 >> 5) * 16384;
#pragma unroll
    for (int f = 0; f < 16; ++f) Qf[f] = *(const bf16x8*)(qb + f * 1024 + l * 16);
  }

  f32x16 O[8];
#pragma unroll
  for (int c = 0; c < 8; ++c)
#pragma unroll
    for (int r = 0; r < 16; ++r) O[c][r] = 0.f;
  float lsum = 0.f;
  const float L2E = 1.442695041f;

  __syncthreads();

  for (int t = 0; t < KT; ++t) {
    const int cur = t & 1;
    if (t + 1 < KT) {  // prefetch next tile into other buffer
      const size_t gt = gbase + (size_t)(t + 1) * 16384;
      const int nb = cur ^ 1;
#pragma unroll
      for (int r = 0; r < 4; ++r)
        g2l16(xn + gt + r * 4096 + tid * 16, &sK[nb][r * 4096 + tid * 16]);
#pragma unroll
      for (int r = 0; r < 3; ++r)
        g2l16(vt + gt + 4096 + r * 4096 + tid * 16, &sV[nb][r * 4096 + tid * 16]);
    }
    const unsigned char* Kb = &sK[cur][0];
    const unsigned char* Vb = &sV[cur][0];

    // ---- St[32k][32q] = K . Q^T over d=256 (16 frags)
    f32x16 St;
#pragma unroll
    for (int r = 0; r < 16; ++r) St[r] = 0.f;
    __builtin_amdgcn_s_setprio(1);
#pragma unroll
    for (int f = 0; f < 16; ++f) {
      const bf16x8 ka = *(const bf16x8*)(Kb + f * 1024 + l * 16);
      St = __builtin_amdgcn_mfma_f32_32x32x16_bf16(ka, Qf[f], St, 0, 0, 0);
    }
    __builtin_amdgcn_s_setprio(0);

    // ---- V frags 0..3 (c=0,1) direct from L2: issue NOW, consume after
    // softmax (~300cy of cover). Reg cost overlaps dying St.
    const bf16x8* Vg = (const bf16x8*)(vt + gbase + (size_t)t * 16384);
    const bf16x8 vg0 = Vg[0 * 64 + l];
    const bf16x8 vg1 = Vg[1 * 64 + l];
    const bf16x8 vg2 = Vg[2 * 64 + l];
    const bf16x8 vg3 = Vg[3 * 64 + l];

    // ---- p = exp(s - 1) = exp2(s*log2e - log2e) (fixed shift; exact)
    float p[16];
#pragma unroll
    for (int r = 0; r < 16; ++r) p[r] = exp2f(fmaf(St[r], L2E, -L2E));
    // tree rowsum (reassociated; no 16-deep serial chain)
    {
      float s0 = (p[0] + p[1]) + (p[2] + p[3]);
      float s1 = (p[4] + p[5]) + (p[6] + p[7]);
      float s2 = (p[8] + p[9]) + (p[10] + p[11]);
      float s3 = (p[12] + p[13]) + (p[14] + p[15]);
      lsum += (s0 + s1) + (s2 + s3);
    }
    // ---- pack P^T B-frags: cvt_pk + permlane32_swap (no LDS)
    u32 a0 = cvt_pk(p[0], p[1]), a1 = cvt_pk(p[2], p[3]);
    u32 b0 = cvt_pk(p[4], p[5]), b1 = cvt_pk(p[6], p[7]);
    asm("v_permlane32_swap_b32 %0, %1" : "+v"(a0), "+v"(b0));
    asm("v_permlane32_swap_b32 %0, %1" : "+v"(a1), "+v"(b1));
    u32 c0 = cvt_pk(p[8], p[9]), c1 = cvt_pk(p[10], p[11]);
    u32 d0 = cvt_pk(p[12], p[13]), d1 = cvt_pk(p[14], p[15]);
    asm("v_permlane32_swap_b32 %0, %1" : "+v"(c0), "+v"(d0));
    asm("v_permlane32_swap_b32 %0, %1" : "+v"(c1), "+v"(d1));
    union PW { u32 w[4]; bf16x8 v; } pf0, pf1;
    pf0.w[0] = a0; pf0.w[1] = a1; pf0.w[2] = b0; pf0.w[3] = b1;
    pf1.w[0] = c0; pf1.w[1] = c1; pf1.w[2] = d0; pf1.w[3] = d1;

    // ---- O^T[d][q] += V^T . P^T ; kh=0 pass then kh=1 pass (no same-acc
    // back-to-back). c=0,1 from direct regs; c=2..7 from LDS (frags 4..15).
    __builtin_amdgcn_s_setprio(1);
    O[0] = __builtin_amdgcn_mfma_f32_32x32x16_bf16(vg0, pf0.v, O[0], 0, 0, 0);
    O[1] = __builtin_amdgcn_mfma_f32_32x32x16_bf16(vg2, pf0.v, O[1], 0, 0, 0);
#pragma unroll
    for (int c = 2; c < 8; ++c) {
      const bf16x8 va = *(const bf16x8*)(Vb + (c * 2 - 4) * 1024 + l * 16);
      O[c] = __builtin_amdgcn_mfma_f32_32x32x16_bf16(va, pf0.v, O[c], 0, 0, 0);
    }
    O[0] = __builtin_amdgcn_mfma_f32_32x32x16_bf16(vg1, pf1.v, O[0], 0, 0, 0);
    O[1] = __builtin_amdgcn_mfma_f32_32x32x16_bf16(vg3, pf1.v, O[1], 0, 0, 0);
#pragma unroll
    for (int c = 2; c < 8; ++c) {
      const bf16x8 va = *(const bf16x8*)(Vb + (c * 2 - 3) * 1024 + l * 16);
      O[c] = __builtin_amdgcn_mfma_f32_32x32x16_bf16(va, pf1.v, O[c], 0, 0, 0);
    }
    __builtin_amdgcn_s_setprio(0);
    __syncthreads();
  }

  // ---- epilogue
  const int qc = q0 + lq;
  if (DIRECT) {
    const float Lt = lsum + __shfl_xor(lsum, 32, 64);
    const float sc = 0.1f / Lt;
#pragma unroll
    for (int c = 0; c < 8; ++c)
#pragma unroll
      for (int r = 0; r < 16; ++r) {
        const int d = c * 32 + (r & 3) + 8 * (r >> 2) + 4 * hi;
        out[(size_t)qc * DIMD + d] =
            1.1f * x[(size_t)qc * DIMD + d] - sc * O[c][r];
      }
  } else {
#pragma unroll
    for (int c = 0; c < 8; ++c)
#pragma unroll
      for (int r = 0; r < 16; ++r) {
        const int d = c * 32 + (r & 3) + 8 * (r >> 2) + 4 * hi;
        *(u16*)(Po + ((size_t)split * DIMD + d) * 32768 + (size_t)qc * 2) = f2b(O[c][r]);
      }
    Ls[(size_t)(split * 2 + hi) * NROW + qc] = lsum;
  }
}

// ---------------------------------------------------------------------------
// Merge: out[q][d] = 1.1 x - 0.1 * (sum_s Po[s][d][q]) / (sum_s,h Ls[s][h][q])
template <int NS>
__global__ void cn_merge(const float* __restrict__ x,
                         const unsigned char* __restrict__ Po,
                         const float* __restrict__ Ls,
                         float* __restrict__ out) {
  __shared__ float acc[256][65];
  __shared__ float Lq[64];
  const int t = threadIdx.x;
  const int q0 = blockIdx.x * 64;
  const int dloc = t >> 3, ch = t & 7;
#pragma unroll
  for (int pass = 0; pass < 8; ++pass) {
    const int d = pass * 32 + dloc;
    float a[8] = {0.f, 0.f, 0.f, 0.f, 0.f, 0.f, 0.f, 0.f};
#pragma unroll
    for (int s = 0; s < NS; ++s) {
      const uint4 v = *(const uint4*)(Po + ((size_t)(s * 256 + d)) * 32768 +
                                      (size_t)q0 * 2 + ch * 16);
      const u32 wv[4] = {v.x, v.y, v.z, v.w};
#pragma unroll
      for (int k = 0; k < 4; ++k) {
        a[2 * k + 0] += __uint_as_float(wv[k] << 16);
        a[2 * k + 1] += __uint_as_float(wv[k] & 0xffff0000u);
      }
    }
#pragma unroll
    for (int j = 0; j < 8; ++j) acc[d][ch * 8 + j] = a[j];
  }
  if (t < 64) {
    const int q = q0 + t;
    float L = 0.f;
#pragma unroll
    for (int s = 0; s < NS; ++s)
      L += Ls[(size_t)(s * 2 + 0) * NROW + q] + Ls[(size_t)(s * 2 + 1) * NROW + q];
    Lq[t] = 1.0f / L;
  }
  __syncthreads();
  const int ql = t >> 2, dd0 = (t & 3) * 64;
  const float inv = Lq[ql];
  const int q = q0 + ql;
#pragma unroll
  for (int i = 0; i < 64; i += 4) {
    const float4 xv = *(const float4*)(x + (size_t)q * DIMD + dd0 + i);
    float4 ov;
    ov.x = 1.1f * xv.x - 0.1f * acc[dd0 + i + 0][ql] * inv;
    ov.y = 1.1f * xv.y - 0.1f * acc[dd0 + i + 1][ql] * inv;
    ov.z = 1.1f * xv.z - 0.1f * acc[dd0 + i + 2][ql] * inv;
    ov.w = 1.1f * xv.w - 0.1f * acc[dd0 + i + 3][ql] * inv;
    *(float4*)(out + (size_t)q * DIMD + dd0 + i) = ov;
  }
}

// ---------------------------------------------------------------------------
extern "C" void kernel_launch(void* const* d_in, const int* in_sizes, int n_in,
                              void* d_out, int out_size, void* d_ws, size_t ws_size,
                              hipStream_t stream) {
  const float* x = (const float*)d_in[0];
  float* out = (float*)d_out;
  unsigned char* xn = (unsigned char*)d_ws;                      // 8 MB packed bf16 x_norm
  unsigned char* vt = xn + (size_t)8 * 1024 * 1024;              // 8 MB packed bf16 V^T
  unsigned char* Po = vt + (size_t)8 * 1024 * 1024;              // NS * 8 MB bf16 partials

  cn_norm<<<4096, 256, 0, stream>>>(x, xn);
  cn_vtpack<<<512, 256, 0, stream>>>(x, vt);

  const size_t need4 = (size_t)(16 + 32) * 1024 * 1024 + 512 * 1024;
  const size_t need2 = (size_t)(16 + 16) * 1024 * 1024 + 256 * 1024;
  if (ws_size >= need4) {
    float* Ls = (float*)(Po + (size_t)4 * 8 * 1024 * 1024);
    cn_flash<4, false><<<512, 256, 0, stream>>>(xn, vt, Po, Ls, x, out);
    cn_merge<4><<<256, 256, 0, stream>>>(x, Po, Ls, out);
  } else if (ws_size >= need2) {
    float* Ls = (float*)(Po + (size_t)2 * 8 * 1024 * 1024);
    cn_flash<2, false><<<256, 256, 0, stream>>>(xn, vt, Po, Ls, x, out);
    cn_merge<2><<<256, 256, 0, stream>>>(x, Po, Ls, out);
  } else {
    cn_flash<1, true><<<128, 256, 0, stream>>>(xn, vt, nullptr, nullptr, x, out);
  }
}